// Round 9
// baseline (136.425 us; speedup 1.0000x reference)
//
#include <hip/hip_runtime.h>

// Problem constants (from reference setup_inputs)
#define B_   32
#define T_   4096
#define D_   128
#define TU   512
#define M_   8
#define O_   64      // Dout
#define HW   64      // d-columns per half
#define TILE (TU * HW)   // 32768 words = 128 KB per (b,half,quarter) tile
#define TSL  1024    // rows per scatter block (T_/4)
#define BN_EPS 1e-5f

// 16 B vector with 4 B alignment: feat windows start at +1 float within the
// 516 B row, so only element-aligned; gfx950 handles line straddle in HW.
typedef float f4u __attribute__((ext_vector_type(4), aligned(4)));

// ws (float) layout: 256 tiles of [512][64] partial-max hid = 32 MB.
// (The harness's own per-iteration ws poison writes 258 MB -> space exists.)

// ---------------------------------------------------------------------------
// R9: gather architecture was imbalance-limited (half-wave per Binomial-7.2
// bin; block = max of 32 bins ~ 2.5x straggler; R7/R8 indirection fixes both
// neutral). Return to DENSE scatter (uniform work, no indirection) and fix
// R4's math bug: partial tiles are MAX-combined in K2 before the matmul,
// never summed.
//   K1 scatter: block=(b,half,quarter): zero LDS hid[512][64]; uidx for its
//     1024 rows; dense scan 16 lanes/row x 256 B contiguous, 8-deep bursts;
//     LDS atomicMax (uint bits == float max for non-negative, init 0);
//     dump raw tile to ws (coalesced float4).
//   K2 merge: block=(b,uc32): for each bin, fmax the 4 quarter-tiles,
//     fold BN+conv+fc, PDOT + shfl-reduce, write out.
// XCD swizzle both kernels: all blocks of batch b share one XCD.
// ---------------------------------------------------------------------------

__global__ __launch_bounds__(1024) void scatter_kernel(
    const float* __restrict__ x,        // (B,T,129): [...,0]=tw, [...,1:]=feats
    const int*   __restrict__ mask,     // (B,T) as int32
    const float* __restrict__ tw_uniq,  // (B,Tu)
    float*       __restrict__ wsF) {
    __shared__ unsigned hid[TILE];      // 128 KB, quad-XOR swizzled by u
    __shared__ int uidxs[TSL];          // 4 KB
    const int i = blockIdx.x;           // 0..255
    const int b = (i & 7) + 8 * ((i >> 3) & 3);
    const int r = i >> 5;               // 0..7
    const int h = r >> 2;               // d-half 0/1
    const int q = r & 3;                // t-quarter 0..3
    const int tid = threadIdx.x;
    const int tb = q * TSL;

    const float* xb = x + (size_t)b * T_ * (D_ + 1);

    // ---- phase A: issue per-row tw/mask loads (1 row/thread) ----
    const float twf = xb[(size_t)(tb + tid) * (D_ + 1)];   // row word 0
    const int   mk  = mask[b * T_ + tb + tid];
    const float u0  = tw_uniq[b * TU];

    // ---- phase B: zero hid (contiguous float4 per wave, conflict-free) ----
#pragma unroll
    for (int c = 0; c < TILE / 4096; ++c)
        *(float4*)&hid[c * 4096 + tid * 4] = make_float4(0.f, 0.f, 0.f, 0.f);

    uidxs[tid] = mk ? min(max((int)(twf - u0), 0), TU - 1) : -1;
    __syncthreads();

    // ---- phase C: dense scan, 8-deep bursts; LDS atomicMax scatter ----
    const int rloc = tid >> 4;          // 0..63: row within pass
    const int lq   = tid & 15;          // d-quad within half
    const float* fb = xb + 1 + h * HW + lq * 4;
    for (int it = 0; it < TSL / 64 / 8; ++it) {    // 2 iterations
        f4u fv[8];
        int uu[8];
#pragma unroll
        for (int j = 0; j < 8; ++j) {
            const int t = tb + (it * 8 + j) * 64 + rloc;
            fv[j] = *(const f4u*)(fb + (size_t)t * (D_ + 1));
        }
#pragma unroll
        for (int j = 0; j < 8; ++j)
            uu[j] = uidxs[(it * 8 + j) * 64 + rloc];   // 16 lanes: broadcast
#pragma unroll
        for (int j = 0; j < 8; ++j) {
            if (uu[j] >= 0) {
                // physical quad slot = lq ^ (u&15): spreads phase-D/K2 access
                unsigned* hp = &hid[(uu[j] << 6) + ((lq ^ (uu[j] & 15)) << 2)];
                if (fv[j].x > 0.f) atomicMax(hp + 0, __float_as_uint(fv[j].x));
                if (fv[j].y > 0.f) atomicMax(hp + 1, __float_as_uint(fv[j].y));
                if (fv[j].z > 0.f) atomicMax(hp + 2, __float_as_uint(fv[j].z));
                if (fv[j].w > 0.f) atomicMax(hp + 3, __float_as_uint(fv[j].w));
            }
        }
    }
    __syncthreads();

    // ---- phase D: dump tile to ws (coalesced float4; swizzle kept) ----
    float* tp = wsF + (size_t)(((b * 2 + h) << 2) + q) * TILE;
#pragma unroll
    for (int c = 0; c < TILE / 4096; ++c)
        *(float4*)(tp + c * 4096 + tid * 4) = *(const float4*)&hid[c * 4096 + tid * 4];
}

// grid 512 = (b x 16 u-chunks of 32), 1024 thr = 16 waves; ONE bin per
// half-wave (work here is uniform: 4 fmax-loads + PDOT regardless of bin).
__global__ __launch_bounds__(1024) void merge_mm_kernel(
    const float* __restrict__ bn_gamma, const float* __restrict__ bn_beta,
    const float* __restrict__ bn_mean,  const float* __restrict__ bn_var,
    const float* __restrict__ conv_w,   const float* __restrict__ conv_b,
    const float* __restrict__ fc_w,     const float* __restrict__ fc_b,
    const float* __restrict__ wsF, float* __restrict__ out) {
    __shared__ float wsm[M_ * D_];   // folded weights Weff[m][d], 4 KB
    __shared__ float tmp[M_ * D_];
    __shared__ float biasc[M_];
    const int j = blockIdx.x;
    const int b  = (j & 7) + 8 * ((j >> 3) & 3);
    const int uc = j >> 5;                          // 0..15
    const int tid = threadIdx.x;

    // ---- fold BN+conv+fc: tid = m*128 + d (exactly 1024 threads) ----
    {
        const int m = tid >> 7, d = tid & (D_ - 1);
        float wraw = 0.f;
        for (int o = 0; o < O_; ++o) wraw += fc_w[m * O_ + o] * conv_w[o * D_ + d];
        const float sc = bn_gamma[d] * rsqrtf(bn_var[d] + BN_EPS);
        const float sh = bn_beta[d] - bn_mean[d] * sc;
        wsm[tid] = wraw * sc;
        tmp[tid] = wraw * sh;
    }
    __syncthreads();
    if (tid < M_) {
        float s = fc_b[tid];
        for (int o = 0; o < O_; ++o) s += fc_w[tid * O_ + o] * conv_b[o];
        for (int d = 0; d < D_; ++d) s += tmp[tid * D_ + d];
        biasc[tid] = s;
    }
    __syncthreads();

    const int w    = tid >> 6;        // wave 0..15
    const int lane = tid & 63;
    const int half = lane >> 5;       // bin selector within wave
    const int l5   = lane & 31;       // d-quad 0..31 (d = l5*4..+3)
    const int u    = uc * 32 + w * 2 + half;
    const int hh   = l5 >> 4;         // which d-half tile
    const int dq   = l5 & 15;         // quad within half
    const int slot = dq ^ (u & 15);   // unswizzle K1's layout

    const float* tp = wsF + (size_t)((b * 2 + hh) << 2) * TILE + u * HW + slot * 4;
    const float4 v0 = *(const float4*)(tp);
    const float4 v1 = *(const float4*)(tp + TILE);
    const float4 v2 = *(const float4*)(tp + 2 * TILE);
    const float4 v3 = *(const float4*)(tp + 3 * TILE);
    const float a0 = fmaxf(fmaxf(v0.x, v1.x), fmaxf(v2.x, v3.x));
    const float a1 = fmaxf(fmaxf(v0.y, v1.y), fmaxf(v2.y, v3.y));
    const float a2 = fmaxf(fmaxf(v0.z, v1.z), fmaxf(v2.z, v3.z));
    const float a3 = fmaxf(fmaxf(v0.w, v1.w), fmaxf(v2.w, v3.w));

    // partial dots: this lane owns d = l5*4..l5*4+3
    const int db = l5 << 2;
    float p0, p1, p2, p3, p4, p5, p6, p7;
#define PDOT(mm) (a0 * wsm[(mm) * D_ + db] + a1 * wsm[(mm) * D_ + db + 1] + \
                  a2 * wsm[(mm) * D_ + db + 2] + a3 * wsm[(mm) * D_ + db + 3])
    p0 = PDOT(0); p1 = PDOT(1); p2 = PDOT(2); p3 = PDOT(3);
    p4 = PDOT(4); p5 = PDOT(5); p6 = PDOT(6); p7 = PDOT(7);
#undef PDOT
    // reduce across the 32 lanes of this half (xor offsets < 32 stay in-half)
#pragma unroll
    for (int off = 1; off < 32; off <<= 1) {
        p0 += __shfl_xor(p0, off); p1 += __shfl_xor(p1, off);
        p2 += __shfl_xor(p2, off); p3 += __shfl_xor(p3, off);
        p4 += __shfl_xor(p4, off); p5 += __shfl_xor(p5, off);
        p6 += __shfl_xor(p6, off); p7 += __shfl_xor(p7, off);
    }
    if (l5 == 0) {                    // lane 0 and lane 32 write their bins
        float* op = out + ((size_t)(b * TU + u)) * M_;
        *(float4*)(op)     = make_float4(p0 + biasc[0], p1 + biasc[1],
                                         p2 + biasc[2], p3 + biasc[3]);
        *(float4*)(op + 4) = make_float4(p4 + biasc[4], p5 + biasc[5],
                                         p6 + biasc[6], p7 + biasc[7]);
    }
}

extern "C" void kernel_launch(void* const* d_in, const int* in_sizes, int n_in,
                              void* d_out, int out_size, void* d_ws, size_t ws_size,
                              hipStream_t stream) {
    const float* x        = (const float*)d_in[0];   // (32,4096,129) f32
    const int*   mask     = (const int*)  d_in[1];   // (32,4096,1) bool->int32
    const float* tw_uniq  = (const float*)d_in[2];   // (32,512,1) f32
    const float* bn_gamma = (const float*)d_in[3];
    const float* bn_beta  = (const float*)d_in[4];
    const float* bn_mean  = (const float*)d_in[5];
    const float* bn_var   = (const float*)d_in[6];
    const float* conv_w   = (const float*)d_in[7];   // (64,128)
    const float* conv_b   = (const float*)d_in[8];   // (64,)
    const float* fc_w     = (const float*)d_in[9];   // (8,64)
    const float* fc_b     = (const float*)d_in[10];  // (8,)
    float* wsF = (float*)d_ws;                       // 32 MB partial-hid tiles
    float* out = (float*)d_out;                      // (32,512,8) f32

    scatter_kernel<<<256, 1024, 0, stream>>>(x, mask, tw_uniq, wsF);
    merge_mm_kernel<<<512, 1024, 0, stream>>>(
        bn_gamma, bn_beta, bn_mean, bn_var,
        conv_w, conv_b, fc_w, fc_b, wsF, out);
}

// Round 10
// 125.866 us; speedup vs baseline: 1.0839x; 1.0839x over previous
//
#include <hip/hip_runtime.h>

// Problem constants (from reference setup_inputs)
#define B_   32
#define T_   4096
#define D_   128
#define TU   512
#define M_   8
#define O_   64      // Dout
#define UCH  64      // u-bins per block
#define PADW 132     // hid row stride in words (pad: rows offset banks by 4)
#define LCAP 2048    // list capacity (mean 460, sigma ~20 -> 79 sigma)
#define BN_EPS 1e-5f

// 16 B vector with 4 B alignment: feat windows start at +1 float within the
// 516 B row, so only element-aligned; gfx950 handles line straddle in HW.
typedef float f4u __attribute__((ext_vector_type(4), aligned(4)));

// ---------------------------------------------------------------------------
// R10 synthesis: every prior architecture hit ~47us with a different limiter:
// sparse 16B@516B loads (R0-R3), per-bin straggler imbalance (R5-R8), ws
// round-trip (R9). This kernel dodges all three: block = (b, u-chunk of 64)
// owns u-range x FULL D, so max is block-local -> no ws, no merge, no device
// atomics, ONE launch.
//   A: read batch's tw/mask (8 sibling blocks share lines in XCD L2 via
//      swizzle); ballot-compact in-range rows into a block-local LDS list
//      (~460 +- 20; 4% spread -> imbalance averages away).
//   B: half-wave gathers list rows as FULL 512 B contiguous reads (32 lanes
//      x 16 B), 8-deep bursts; each masked row read once device-wide.
//   C: LDS atomicMax into hid[64][132] (uint bits == float max, init 0).
//   D: fold BN+conv+fc, PDOT + shfl-reduce (proven epilogue), write out.
// XCD swizzle: b = (i&7) + 8*((i>>3)&3), uc = i>>5  -> all 8 blocks of a
// batch land on one XCD (i&7 == b&7).
// ---------------------------------------------------------------------------
__global__ __launch_bounds__(1024) void fused_kernel(
    const float* __restrict__ x,        // (B,T,129): [...,0]=tw, [...,1:]=feats
    const int*   __restrict__ mask,     // (B,T) as int32
    const float* __restrict__ tw_uniq,  // (B,Tu)
    const float* __restrict__ bn_gamma,
    const float* __restrict__ bn_beta,
    const float* __restrict__ bn_mean,
    const float* __restrict__ bn_var,
    const float* __restrict__ conv_w,   // (64,128)
    const float* __restrict__ conv_b,   // (64,)
    const float* __restrict__ fc_w,     // (8,64)
    const float* __restrict__ fc_b,     // (8,)
    float*       __restrict__ out) {    // (32,512,8)
    __shared__ unsigned hid[UCH * PADW];   // 33.8 KB
    __shared__ int   list[LCAP];           // 8 KB: t | (u_local<<12)
    __shared__ float wsm[M_ * D_];         // 4 KB folded weights
    __shared__ float tmp[M_ * D_];
    __shared__ float biasc[M_];
    __shared__ int   nlist;
    const int i   = blockIdx.x;            // 0..255
    const int b   = (i & 7) + 8 * ((i >> 3) & 3);
    const int uc  = i >> 5;                // 0..7
    const int tid = threadIdx.x;
    const int u_lo = uc * UCH;

    const float* xb = x + (size_t)b * T_ * (D_ + 1);

    // ---- A: issue tw/mask loads first (latency hides under weight fold) ----
    float twf[4]; int mk[4];
#pragma unroll
    for (int k = 0; k < 4; ++k) {
        const int t = k * 1024 + tid;
        twf[k] = xb[(size_t)t * (D_ + 1)];     // row word 0
        mk[k]  = mask[b * T_ + t];
    }
    const float u0 = tw_uniq[b * TU];

    if (tid == 0) nlist = 0;
    for (int p = tid; p < UCH * PADW; p += 1024) hid[p] = 0u;

    // ---- fold BN+conv+fc: tid = m*128 + d ----
    {
        const int m = tid >> 7, d = tid & (D_ - 1);
        float wraw = 0.f;
        for (int o = 0; o < O_; ++o) wraw += fc_w[m * O_ + o] * conv_w[o * D_ + d];
        const float sc = bn_gamma[d] * rsqrtf(bn_var[d] + BN_EPS);
        const float sh = bn_beta[d] - bn_mean[d] * sc;
        wsm[tid] = wraw * sc;
        tmp[tid] = wraw * sh;
    }
    __syncthreads();
    if (tid < M_) {
        float s = fc_b[tid];
        for (int o = 0; o < O_; ++o) s += fc_w[tid * O_ + o] * conv_b[o];
        for (int d = 0; d < D_; ++d) s += tmp[tid * D_ + d];
        biasc[tid] = s;
    }

    // ---- A2: ballot-compact in-range rows into the list ----
    const int lane = tid & 63;
#pragma unroll
    for (int k = 0; k < 4; ++k) {
        const int t = k * 1024 + tid;
        const int u = min(max((int)(twf[k] - u0), 0), TU - 1);
        const int ul = u - u_lo;
        const bool want = (mk[k] != 0) && (ul >= 0) && (ul < UCH);
        const unsigned long long bal = __ballot(want);
        if (bal) {
            const int cnt = __popcll(bal);
            const int leader = __ffsll((long long)bal) - 1;
            int base = 0;
            if (lane == leader) base = atomicAdd(&nlist, cnt);
            base = __shfl(base, leader);
            if (want) {
                const int pos = base + __popcll(bal & ((1ull << lane) - 1ull));
                if (pos < LCAP) list[pos] = t | (ul << 12);
            }
        }
    }
    __syncthreads();
    const int n = min(nlist, LCAP);

    // ---- B+C: gather full rows (512 B contiguous), 8-deep bursts; scatter ----
    const int hw = tid >> 5;          // half-wave 0..31 (hw = 2w + lane>>5)
    const int l5 = tid & 31;          // d-quad: d = l5*4..+3 (full row/half-wave)
    for (int be = 0; be < n; be += 32 * 8) {
        f4u fv[8]; int uu[8], ok[8];
#pragma unroll
        for (int k = 0; k < 8; ++k) {
            const int e = be + k * 32 + hw;
            ok[k] = (e < n);
            const int ent = list[ok[k] ? e : 0];   // clamped dup: harmless
            uu[k] = ent >> 12;
            fv[k] = *(const f4u*)(xb + (size_t)(ent & 4095) * (D_ + 1) + 1 + (l5 << 2));
        }
#pragma unroll
        for (int k = 0; k < 8; ++k) {
            if (ok[k]) {
                unsigned* hp = &hid[uu[k] * PADW + (l5 << 2)];
                if (fv[k].x > 0.f) atomicMax(hp + 0, __float_as_uint(fv[k].x));
                if (fv[k].y > 0.f) atomicMax(hp + 1, __float_as_uint(fv[k].y));
                if (fv[k].z > 0.f) atomicMax(hp + 2, __float_as_uint(fv[k].z));
                if (fv[k].w > 0.f) atomicMax(hp + 3, __float_as_uint(fv[k].w));
            }
        }
    }
    __syncthreads();

    // ---- D: per-bin epilogue (half-wave per bin, 2 bins each) ----
#pragma unroll
    for (int it = 0; it < 2; ++it) {
        const int ul = hw + it * 32;                  // 0..63
        const int u  = u_lo + ul;
        const uint4 hb = *(const uint4*)&hid[ul * PADW + (l5 << 2)];
        const float a0 = __uint_as_float(hb.x);
        const float a1 = __uint_as_float(hb.y);
        const float a2 = __uint_as_float(hb.z);
        const float a3 = __uint_as_float(hb.w);
        const int db = l5 << 2;
        float p0, p1, p2, p3, p4, p5, p6, p7;
#define PDOT(mm) (a0 * wsm[(mm) * D_ + db] + a1 * wsm[(mm) * D_ + db + 1] + \
                  a2 * wsm[(mm) * D_ + db + 2] + a3 * wsm[(mm) * D_ + db + 3])
        p0 = PDOT(0); p1 = PDOT(1); p2 = PDOT(2); p3 = PDOT(3);
        p4 = PDOT(4); p5 = PDOT(5); p6 = PDOT(6); p7 = PDOT(7);
#undef PDOT
#pragma unroll
        for (int off = 1; off < 32; off <<= 1) {      // stays within half
            p0 += __shfl_xor(p0, off); p1 += __shfl_xor(p1, off);
            p2 += __shfl_xor(p2, off); p3 += __shfl_xor(p3, off);
            p4 += __shfl_xor(p4, off); p5 += __shfl_xor(p5, off);
            p6 += __shfl_xor(p6, off); p7 += __shfl_xor(p7, off);
        }
        if (l5 == 0) {
            float* op = out + ((size_t)(b * TU + u)) * M_;
            *(float4*)(op)     = make_float4(p0 + biasc[0], p1 + biasc[1],
                                             p2 + biasc[2], p3 + biasc[3]);
            *(float4*)(op + 4) = make_float4(p4 + biasc[4], p5 + biasc[5],
                                             p6 + biasc[6], p7 + biasc[7]);
        }
    }
}

extern "C" void kernel_launch(void* const* d_in, const int* in_sizes, int n_in,
                              void* d_out, int out_size, void* d_ws, size_t ws_size,
                              hipStream_t stream) {
    const float* x        = (const float*)d_in[0];   // (32,4096,129) f32
    const int*   mask     = (const int*)  d_in[1];   // (32,4096,1) bool->int32
    const float* tw_uniq  = (const float*)d_in[2];   // (32,512,1) f32
    const float* bn_gamma = (const float*)d_in[3];
    const float* bn_beta  = (const float*)d_in[4];
    const float* bn_mean  = (const float*)d_in[5];
    const float* bn_var   = (const float*)d_in[6];
    const float* conv_w   = (const float*)d_in[7];   // (64,128)
    const float* conv_b   = (const float*)d_in[8];   // (64,)
    const float* fc_w     = (const float*)d_in[9];   // (8,64)
    const float* fc_b     = (const float*)d_in[10];  // (8,)
    float* out = (float*)d_out;                      // (32,512,8) f32

    fused_kernel<<<256, 1024, 0, stream>>>(
        x, mask, tw_uniq, bn_gamma, bn_beta, bn_mean, bn_var,
        conv_w, conv_b, fc_w, fc_b, out);
}